// Round 8
// baseline (262.661 us; speedup 1.0000x reference)
//
#include <hip/hip_runtime.h>
#include <stdint.h>

#define LOG_N 12
#define N 4096
#define NPAIR 2048
#define ROWS 8
#define NT 512
#define TWA_QUADS (12*512)   // reorganized phase-A twiddles: 96 KB in d_ws

// LDS bank-deconflict swizzle: bijection on [0,4096); <=2-way bank aliasing
// for all 4 ownership patterns (contig, stride-8, -64, -512). Only touches
// bits 2..5, keyed on bits >=3 -> aligned 64-blocks map onto themselves, so
// wave-private slices stay wave-private.
__device__ __forceinline__ int swz(int e){
  return e ^ (((e>>6)&7)<<3) ^ (((e>>3)&1)<<2);
}

// In-wave LDS ordering fence. r7 measured: REMOVING these is -10% — without
// them the RA optimizes for register economy (VGPR 64->36) and de-pipelines
// the twiddle loads. Keep them (r5 structure).
__device__ __forceinline__ void wave_fence(){
  asm volatile("s_waitcnt lgkmcnt(0)" ::: "memory");
  __builtin_amdgcn_sched_barrier(0);
}

// ---- Preprocess: transpose phase-A twiddles so thread t's m-th quad of
// stage ls sits at twA[(ls*4+m)*512 + t] (lane-stride 16 B -> coalesced).
__global__ void reorg_twA(const float4* __restrict__ tw, float4* __restrict__ twA){
  const int b = blockIdx.x;      // b = ls*4+m, 12 blocks
  const int t = threadIdx.x;     // 512 threads
  const int ls = b >> 2, m = b & 3;
  twA[b*NT + t] = tw[ls*NPAIR + 4*t + m];
}

// Phase A (stages 0,1,2) from reorganized twiddles: coalesced loads.
__device__ __forceinline__ void phaseA(float (&v)[ROWS][8], int t,
                                       const float4* __restrict__ twA){
#pragma unroll
  for(int sub=0; sub<3; ++sub){
#pragma unroll
    for(int m=0;m<4;++m){
      const int k0 = (sub==0) ? (2*m) : (sub==1) ? (((m>>1)<<2)|(m&1)) : m;
      const int k1 = k0 + (1<<sub);
      const float4 q = twA[(sub*4+m)*NT + t];
#pragma unroll
      for(int r=0;r<ROWS;++r){
        const float x0=v[r][k0], x1=v[r][k1];
        v[r][k0] = fmaf(q.x,x0,q.y*x1);
        v[r][k1] = fmaf(q.z,x0,q.w*x1);
      }
    }
  }
}

// One radix-8 phase = 3 butterfly stages; element k of each row is at
// global position base + (k << LS0). LS0 = 3,6,9 (lane-contiguous twiddle
// access). With ROWS=8, each quad load feeds 16 FMAs (2x better VMEM
// amortization than r5; twiddle L2 traffic and instr count both halve).
template<int LS0>
__device__ __forceinline__ void phase3(float (&v)[ROWS][8], int base,
                                       const float4* __restrict__ twq4){
#pragma unroll
  for(int sub=0; sub<3; ++sub){
    const int ls = LS0 + sub;
    const float4* __restrict__ twq = twq4 + ls*NPAIR;
#pragma unroll
    for(int m=0;m<4;++m){
      const int k0 = (sub==0) ? (2*m) : (sub==1) ? (((m>>1)<<2)|(m&1)) : m;
      const int k1 = k0 + (1<<sub);
      const int pos0 = base + (k0<<LS0);
      const int p = ((pos0>>(ls+1))<<ls) | (pos0 & ((1<<ls)-1));
      const float4 q = twq[p];
#pragma unroll
      for(int r=0;r<ROWS;++r){
        const float x0=v[r][k0], x1=v[r][k1];
        v[r][k0] = fmaf(q.x,x0,q.y*x1);
        v[r][k1] = fmaf(q.z,x0,q.w*x1);
      }
    }
  }
}

// ROUND-8: ROWS=8. Invariant found (r4/r5/r7): waves x VGPR ~= const (SIMD
// reg pool) -> outstanding-memory capacity is FIXED; perf is set by twiddle
// VMEM demand. Twiddle traffic/instrs ~ 1/ROWS (zero intra-block reuse:
// each block reads 384 KB of twiddles from L2 once). ROWS 4->2 cost +53us
// (r4); ROWS 4->8 should recover ~ -20us. launch_bounds(512,2): measured cap
// law 256/arg -> 128 VGPR; demand ~64 (v) + in-flight quads + addr ~ 100.
__global__ __launch_bounds__(NT, 2)
void butterfly_k(const float* __restrict__ x, const float* __restrict__ tw,
                 const float4* __restrict__ twA, float* __restrict__ out)
{
  __shared__ float lds[4*N];            // 64 KB: 4-row pump buffer, 2 passes
  const int t = threadIdx.x;
  const size_t row0 = (size_t)blockIdx.x * ROWS;
  const float4* twq4 = (const float4*)tw;

  float v[ROWS][8];

  // ---- global load, phase-A ownership: e = 8t + k (2 x dwordx4 per row)
  {
    const float4* px = (const float4*)x;
#pragma unroll
    for(int r=0;r<ROWS;++r){
      const float4 a = px[(row0+r)*(N/4) + 2*t];
      const float4 b = px[(row0+r)*(N/4) + 2*t + 1];
      v[r][0]=a.x; v[r][1]=a.y; v[r][2]=a.z; v[r][3]=a.w;
      v[r][4]=b.x; v[r][5]=b.y; v[r][6]=b.z; v[r][7]=b.w;
    }
  }

  phaseA(v, t, twA);                    // stages 0,1,2 — coalesced twiddles

  const int baseB = ((t>>3)<<6) | (t&7);
  // ---- exchange A -> B: wave-private (8-thread groups). 4 rows per pass,
  // 2 passes through the 64 KB buffer. In-order DS + fences give W->R and
  // R(pass0)->W(pass1) ordering within the wave.
  {
    const int Bb = (8*t) ^ (((t>>3)&7)<<3);
    const int flip = (t&1)<<2;
#pragma unroll
    for(int pp=0;pp<2;++pp){
      wave_fence();                     // pp=1: pass-0 reads retired first
#pragma unroll
      for(int rr=0;rr<4;++rr){
        float* L = lds + rr*N;
        const int r = 4*pp + rr;
        *(float4*)(L + Bb + flip)     = make_float4(v[r][0],v[r][1],v[r][2],v[r][3]);
        *(float4*)(L + Bb + (4^flip)) = make_float4(v[r][4],v[r][5],v[r][6],v[r][7]);
      }
      wave_fence();
#pragma unroll
      for(int k=0;k<8;++k){
        const int a = swz(baseB + (k<<3));
#pragma unroll
        for(int rr=0;rr<4;++rr) v[4*pp+rr][k] = lds[rr*N + a];
      }
    }
  }

  phase3<3>(v, baseB, twq4);            // stages 3,4,5 (strides 8,16,32)

  const int baseC = ((t>>6)<<9) | (t&63);
  // ---- exchange B -> C: wave-private (64-thread groups = one wave).
#pragma unroll
  for(int pp=0;pp<2;++pp){
    wave_fence();
#pragma unroll
    for(int k=0;k<8;++k){
      const int a = swz(baseB + (k<<3));
#pragma unroll
      for(int rr=0;rr<4;++rr) lds[rr*N + a] = v[4*pp+rr][k];
    }
    wave_fence();
#pragma unroll
    for(int k=0;k<8;++k){
      const int a = swz(baseC + (k<<6));
#pragma unroll
      for(int rr=0;rr<4;++rr) v[4*pp+rr][k] = lds[rr*N + a];
    }
  }

  phase3<6>(v, baseC, twq4);            // stages 6,7,8 (strides 64,128,256)

  // ---- exchange C -> D: crosses waves. Rows {0..3} then {4..7} through the
  // 64 KB buffer; 3 syncthreads total (C-order writes are wave-private).
  wave_fence();
#pragma unroll
  for(int k=0;k<8;++k){
    const int a = swz(baseC + (k<<6));
#pragma unroll
    for(int rr=0;rr<4;++rr) lds[rr*N + a] = v[rr][k];
  }
  __syncthreads();
#pragma unroll
  for(int k=0;k<8;++k){
    const int a = swz(t + (k<<9));
#pragma unroll
    for(int rr=0;rr<4;++rr) v[rr][k] = lds[rr*N + a];
  }
  __syncthreads();                      // all pass-0 reads done before clobber
#pragma unroll
  for(int k=0;k<8;++k){
    const int a = swz(baseC + (k<<6));
#pragma unroll
    for(int rr=0;rr<4;++rr) lds[rr*N + a] = v[4+rr][k];
  }
  __syncthreads();
#pragma unroll
  for(int k=0;k<8;++k){
    const int a = swz(t + (k<<9));
#pragma unroll
    for(int rr=0;rr<4;++rr) v[4+rr][k] = lds[rr*N + a];
  }

  phase3<9>(v, t, twq4);                // stages 9,10,11 (strides 512,1024,2048)

  // ---- store: element t + 512k of each row; lanes consecutive -> coalesced
#pragma unroll
  for(int r=0;r<ROWS;++r){
    float* po = out + (row0+r)*N + t;
#pragma unroll
    for(int k=0;k<8;++k) po[(size_t)(k<<9)] = v[r][k];
  }
}

extern "C" void kernel_launch(void* const* d_in, const int* in_sizes, int n_in,
                              void* d_out, int out_size, void* d_ws, size_t ws_size,
                              hipStream_t stream) {
  const float* x  = (const float*)d_in[0];   // (8192, 4096) fp32
  const float* tw = (const float*)d_in[1];   // (1,1,12,2048,2,2) fp32
  float* out = (float*)d_out;                // (8192, 4096) fp32
  const int batch = in_sizes[0] / N;         // 8192
  dim3 grid(batch / ROWS), block(NT);

  hipLaunchKernelGGL(reorg_twA, dim3(12), dim3(NT), 0, stream,
                     (const float4*)tw, (float4*)d_ws);
  hipLaunchKernelGGL(butterfly_k, grid, block, 0, stream,
                     x, tw, (const float4*)d_ws, out);
}

// Round 9
// 258.660 us; speedup vs baseline: 1.0155x; 1.0155x over previous
//
#include <hip/hip_runtime.h>
#include <stdint.h>

#define LOG_N 12
#define N 4096
#define NPAIR 2048
#define ROWS 4
#define NT 512
#define TWA_QUADS (12*512)   // reorganized phase-A twiddles: 96 KB in d_ws

// LDS bank-deconflict swizzle: bijection on [0,4096); <=2-way bank aliasing
// for all 4 ownership patterns (contig, stride-8, -64, -512). Only touches
// bits 2..5, keyed on bits >=3 -> aligned 64-blocks map onto themselves, so
// wave-private slices stay wave-private.
__device__ __forceinline__ int swz(int e){
  return e ^ (((e>>6)&7)<<3) ^ (((e>>3)&1)<<2);
}

// ROUND-9 fence: selective sched_barrier instead of lgkmcnt(0)+full wall.
// Facts: (a) r6/r7 PASSED with zero fences -> same-wave DS RAW/WAR needs no
// waitcnt (HW executes a wave's DS ops in order; lgkmcnt returns in-order
// for LDS). (b) r7's -10% was RA de-pipelining (VGPR 64->36) when ALL
// structure vanished. So: pin DS ops in program order (DS not in mask) but
// let VALU/SALU/VMEM_READ cross -> next-phase twiddle loads (global,
// data-independent of the exchange) hoist above the exchange, FMAs consume
// ds_read results incrementally via compiler partial lgkmcnt(N).
// Mask (LLVM SchedGroupMask): VALU=0x2 SALU=0x4 VMEM_READ=0x20.
__device__ __forceinline__ void ds_fence(){
  __builtin_amdgcn_sched_barrier(0x26);
}

// ---- Preprocess: transpose phase-A twiddles so thread t's m-th quad of
// stage ls sits at twA[(ls*4+m)*512 + t] (lane-stride 16 B -> coalesced).
__global__ void reorg_twA(const float4* __restrict__ tw, float4* __restrict__ twA){
  const int b = blockIdx.x;      // b = ls*4+m, 12 blocks
  const int t = threadIdx.x;     // 512 threads
  const int ls = b >> 2, m = b & 3;
  twA[b*NT + t] = tw[ls*NPAIR + 4*t + m];
}

// Phase A (stages 0,1,2) from reorganized twiddles: coalesced loads.
__device__ __forceinline__ void phaseA(float (&v)[ROWS][8], int t,
                                       const float4* __restrict__ twA){
#pragma unroll
  for(int sub=0; sub<3; ++sub){
#pragma unroll
    for(int m=0;m<4;++m){
      const int k0 = (sub==0) ? (2*m) : (sub==1) ? (((m>>1)<<2)|(m&1)) : m;
      const int k1 = k0 + (1<<sub);
      const float4 q = twA[(sub*4+m)*NT + t];
#pragma unroll
      for(int r=0;r<ROWS;++r){
        const float x0=v[r][k0], x1=v[r][k1];
        v[r][k0] = fmaf(q.x,x0,q.y*x1);
        v[r][k1] = fmaf(q.z,x0,q.w*x1);
      }
    }
  }
}

// One radix-8 phase = 3 butterfly stages; element k of each row is at
// global position base + (k << LS0). LS0 = 3,6,9 (lane-contiguous twiddle
// access: ~16 cache lines per wave-instr, the f4 minimum).
template<int LS0>
__device__ __forceinline__ void phase3(float (&v)[ROWS][8], int base,
                                       const float4* __restrict__ twq4){
#pragma unroll
  for(int sub=0; sub<3; ++sub){
    const int ls = LS0 + sub;
    const float4* __restrict__ twq = twq4 + ls*NPAIR;
#pragma unroll
    for(int m=0;m<4;++m){
      const int k0 = (sub==0) ? (2*m) : (sub==1) ? (((m>>1)<<2)|(m&1)) : m;
      const int k1 = k0 + (1<<sub);
      const int pos0 = base + (k0<<LS0);
      const int p = ((pos0>>(ls+1))<<ls) | (pos0 & ((1<<ls)-1));
      const float4 q = twq[p];
#pragma unroll
      for(int r=0;r<ROWS;++r){
        const float x0=v[r][k0], x1=v[r][k1];
        v[r][k0] = fmaf(q.x,x0,q.y*x1);
        v[r][k1] = fmaf(q.z,x0,q.w*x1);
      }
    }
  }
}

// CONSTRAINT BOX (measured r0-r8): VGPR<=64 mandatory (512-thr block needs
// 2 waves/SIMD; effective pool ~256/SIMD; VGPR>64 -> 1 block/CU cliff, r8).
// Within it, ROWS=4 is twiddle-demand-optimal (r4: ROWS2 +53us; r8: ROWS8
// occupancy cliff). r5 = 93.5us. This round: overlap, not demand.
__global__ __launch_bounds__(NT, 4)   // cap 64 VGPR, no spill (r3/r5)
void butterfly_k(const float* __restrict__ x, const float* __restrict__ tw,
                 const float4* __restrict__ twA, float* __restrict__ out)
{
  __shared__ float lds[2*N];            // 32 KB, pair-pumped exchanges
  const int t = threadIdx.x;
  const size_t row0 = (size_t)blockIdx.x * ROWS;
  const float4* twq4 = (const float4*)tw;

  float v[ROWS][8];

  // ---- global load, phase-A ownership: e = 8t + k (2 x dwordx4 per row)
  {
    const float4* px = (const float4*)x;
#pragma unroll
    for(int r=0;r<ROWS;++r){
      const float4 a = px[(row0+r)*(N/4) + 2*t];
      const float4 b = px[(row0+r)*(N/4) + 2*t + 1];
      v[r][0]=a.x; v[r][1]=a.y; v[r][2]=a.z; v[r][3]=a.w;
      v[r][4]=b.x; v[r][5]=b.y; v[r][6]=b.z; v[r][7]=b.w;
    }
  }

  phaseA(v, t, twA);                    // stages 0,1,2 — coalesced twiddles

  const int baseB = ((t>>3)<<6) | (t&7);
  // ---- exchange A -> B: wave-private (8-thread groups). Pair-pumped
  // through the 2-row buffer. Same-wave DS in-order handles RAW (write->
  // read) and WAR (pass-0 reads -> pass-1 writes); ds_fence only pins the
  // DS program order against the scheduler.
  {
    const int Bb = (8*t) ^ (((t>>3)&7)<<3);
    const int flip = (t&1)<<2;
#pragma unroll
    for(int pp=0;pp<2;++pp){
      ds_fence();
#pragma unroll
      for(int rr=0;rr<2;++rr){
        float* L = lds + rr*N;
        const int r = 2*pp + rr;
        *(float4*)(L + Bb + flip)     = make_float4(v[r][0],v[r][1],v[r][2],v[r][3]);
        *(float4*)(L + Bb + (4^flip)) = make_float4(v[r][4],v[r][5],v[r][6],v[r][7]);
      }
      ds_fence();
#pragma unroll
      for(int k=0;k<8;++k){
        const int a = swz(baseB + (k<<3));
#pragma unroll
        for(int rr=0;rr<2;++rr) v[2*pp+rr][k] = lds[rr*N + a];
      }
    }
  }

  phase3<3>(v, baseB, twq4);            // stages 3,4,5 (strides 8,16,32)

  const int baseC = ((t>>6)<<9) | (t&63);
  // ---- exchange B -> C: wave-private (64-thread groups = one wave).
#pragma unroll
  for(int pp=0;pp<2;++pp){
    ds_fence();
#pragma unroll
    for(int k=0;k<8;++k){
      const int a = swz(baseB + (k<<3));
#pragma unroll
      for(int rr=0;rr<2;++rr) lds[rr*N + a] = v[2*pp+rr][k];
    }
    ds_fence();
#pragma unroll
    for(int k=0;k<8;++k){
      const int a = swz(baseC + (k<<6));
#pragma unroll
      for(int rr=0;rr<2;++rr) v[2*pp+rr][k] = lds[rr*N + a];
    }
  }

  phase3<6>(v, baseC, twq4);            // stages 6,7,8 (strides 64,128,256)

  // ---- exchange C -> D: crosses waves. Rows {0,1} then {2,3} through the
  // 32 KB buffer; syncthreads (compiler emits the required waitcnts).
  ds_fence();
#pragma unroll
  for(int k=0;k<8;++k){
    const int a = swz(baseC + (k<<6));
#pragma unroll
    for(int rr=0;rr<2;++rr) lds[rr*N + a] = v[rr][k];
  }
  __syncthreads();
#pragma unroll
  for(int k=0;k<8;++k){
    const int a = swz(t + (k<<9));
#pragma unroll
    for(int rr=0;rr<2;++rr) v[rr][k] = lds[rr*N + a];
  }
  __syncthreads();                      // all pair-0 reads done before clobber
#pragma unroll
  for(int k=0;k<8;++k){
    const int a = swz(baseC + (k<<6));
#pragma unroll
    for(int rr=0;rr<2;++rr) lds[rr*N + a] = v[2+rr][k];
  }
  __syncthreads();
#pragma unroll
  for(int k=0;k<8;++k){
    const int a = swz(t + (k<<9));
#pragma unroll
    for(int rr=0;rr<2;++rr) v[2+rr][k] = lds[rr*N + a];
  }

  phase3<9>(v, t, twq4);                // stages 9,10,11 (strides 512,1024,2048)

  // ---- store: element t + 512k of each row; lanes consecutive -> coalesced
#pragma unroll
  for(int r=0;r<ROWS;++r){
    float* po = out + (row0+r)*N + t;
#pragma unroll
    for(int k=0;k<8;++k) po[(size_t)(k<<9)] = v[r][k];
  }
}

extern "C" void kernel_launch(void* const* d_in, const int* in_sizes, int n_in,
                              void* d_out, int out_size, void* d_ws, size_t ws_size,
                              hipStream_t stream) {
  const float* x  = (const float*)d_in[0];   // (8192, 4096) fp32
  const float* tw = (const float*)d_in[1];   // (1,1,12,2048,2,2) fp32
  float* out = (float*)d_out;                // (8192, 4096) fp32
  const int batch = in_sizes[0] / N;         // 8192
  dim3 grid(batch / ROWS), block(NT);

  hipLaunchKernelGGL(reorg_twA, dim3(12), dim3(NT), 0, stream,
                     (const float4*)tw, (float4*)d_ws);
  hipLaunchKernelGGL(butterfly_k, grid, block, 0, stream,
                     x, tw, (const float4*)d_ws, out);
}